// Round 16
// baseline (658.668 us; speedup 1.0000x reference)
//
#include <hip/hip_runtime.h>

// Problem constants
#define Bq 1024
#define Tq 512
#define Fq 64    // input features
#define Hq 128   // hidden
#define LOG2E 1.44269504089f
#define TWO_LOG2E 2.88539008177f

typedef _Float16 f16;
typedef f16 f16x2 __attribute__((ext_vector_type(2)));
typedef f16 f16x4 __attribute__((ext_vector_type(4)));
typedef f16 f16x8 __attribute__((ext_vector_type(8)));
typedef float f32x4 __attribute__((ext_vector_type(4)));

__device__ __forceinline__ float exp2f_(float x) {
#if __has_builtin(__builtin_amdgcn_exp2f)
    return __builtin_amdgcn_exp2f(x);
#else
    return __expf(x * 0.69314718056f);
#endif
}
__device__ __forceinline__ float rcpf_(float x) {
#if __has_builtin(__builtin_amdgcn_rcpf)
    return __builtin_amdgcn_rcpf(x);
#else
    return 1.f / x;
#endif
}

// compile-time-indexed select of one element of an f32x4 (3 cndmasks)
__device__ __forceinline__ float sel4(f32x4 v, int s) {
    float r = v.x;
    r = (s == 1) ? v.y : r;
    r = (s == 2) ? v.z : r;
    r = (s == 3) ? v.w : r;
    return r;
}

// ---------------- kernel A: decoder fold (one-time, tiny) ----------------
// W_comb = (W_ih_dec @ W_out + W_hh_dec) * lg  (f16, [512][128])
// b_fold = (b_ih+b_hh+W_ih_dec@b_out) * lg     (f32, [512])
// lg = log2e for i,f,o gates; 2*log2e for the g gate (exp2-based pointwise).
__global__ __launch_bounds__(256) void fold_kernel(
    const float* __restrict__ Wih_d, const float* __restrict__ Whh_d,
    const float* __restrict__ bih_d, const float* __restrict__ bhh_d,
    const float* __restrict__ Wout, const float* __restrict__ bout,
    f16* __restrict__ Wcomb, float* __restrict__ bfold)
{
    const int gid = blockIdx.x * 256 + threadIdx.x;   // 0..32767
    const int og = gid >> 6;          // gate row 0..511
    const int oh = (gid & 63) * 2;    // hh pair
    const float lg = ((og >> 7) == 2) ? TWO_LOG2E : LOG2E;
    float ax = Whh_d[(size_t)og * Hq + oh];
    float ay = Whh_d[(size_t)og * Hq + oh + 1];
    for (int f = 0; f < Fq; ++f) {
        float w = Wih_d[(size_t)og * Fq + f];
        float2 o = *(const float2*)(Wout + (size_t)f * Hq + oh);
        ax += w * o.x; ay += w * o.y;
    }
    f16x2 r; r.x = (f16)(ax * lg); r.y = (f16)(ay * lg);
    *(f16x2*)(Wcomb + (size_t)og * Hq + oh) = r;
    if (gid < 512) {
        const float lgb = ((gid >> 7) == 2) ? TWO_LOG2E : LOG2E;
        float b = bih_d[gid] + bhh_d[gid];
        for (int f = 0; f < Fq; ++f)
            b += Wih_d[(size_t)gid * Fq + f] * bout[f];
        bfold[gid] = b * lgb;
    }
}

// ---------------- kernel B: main recurrence ----------------
// 256 blocks x 512 threads (8 waves), 4 batch rows, 1 block/CU.
// r15 base (exp2/rcp pointwise with log2e folded into weights, x-batch,
// bias C-init, folded decoder, 1 barrier/step) + two mechanical cuts:
//  1. Encoder t-loop unrolled x8, decoder x2: tb/buf/par/dt/pk become
//     compile-time -> LDS accesses are base+imm-offset, no per-step
//     address VALU or branch masks.
//  2. x-pass spread: 2 MFMA/step (gate g=dt of the NEXT 4-group) into
//     double-buffered xg[2]; chunk publish moved tb7->tb3 (loads at tb0,
//     ~4-step slack >> 900cyc HBM) so steps tb>=4 may read chunk c+1.
//     Every step is a uniform 18 MFMA; no dt==0 spike.
// Frag layouts (validated r4-r15):
//   A: lane l holds A[l&15][(l>>4)*8+j]   B: lane l holds B[(l>>4)*8+j][l&15]
//   D: lane l reg r = D[(l>>4)*4+r][l&15]
__global__ __launch_bounds__(512)
__attribute__((amdgpu_waves_per_eu(2)))
void lstm_ae_kernel(
    const float* __restrict__ ts,
    const float* __restrict__ Wih_e, const float* __restrict__ Whh_e,
    const float* __restrict__ bih_e, const float* __restrict__ bhh_e,
    const float* __restrict__ Wout, const float* __restrict__ bout,
    const f16* __restrict__ Wcomb, const float* __restrict__ bfold,
    float* __restrict__ out)
{
    const int tid = threadIdx.x;
    const int bid = blockIdx.x;
    const int row0 = bid * 4;

    const int wv = tid >> 6;       // wave 0..7 (owns units wv*16..wv*16+15)
    const int ln = tid & 63;
    const int n16 = ln & 15;       // MFMA N col
    const int kg = ln >> 4;        // k-group 0..3 (D rows kg*4..kg*4+3)
    const int zr = n16 & 3;        // batch row for B-frag AND pointwise col
    const bool act = (n16 < 4);
    const int us = n16 >> 2;       // D-reg select / x-pass time offset
    const int un = kg * 4 + us;    // pointwise: unit (wv*16+un), col zr

    __shared__ alignas(16) f16 hT[2][4][144];            // h dbuf
    __shared__ alignas(16) f16 xS[2][4][8][76];          // x chunk dbuf
    __shared__ alignas(16) float xg[2][8][4][4][4][16];  // x-partials 64KB
    __shared__ float errb[4][4];

    float c_ = 0.f;     // one unit (wv*16+un), one batch col (zr)
    f32x4 bias4[4];     // scaled bias, C-init of the x-pass / decoder chain

    // ===================== encoder setup =====================
    f16x8 wf[4][6];   // A-frags [gate][k-tile], 96 VGPR (log2e-scaled)
#pragma unroll
    for (int g = 0; g < 4; ++g) {
        const float fg = (g == 2) ? TWO_LOG2E : LOG2E;
        const int gr = g * 128 + wv * 16 + n16;
#pragma unroll
        for (int kt = 0; kt < 6; ++kt) {
            const int kc = kt * 32 + kg * 8;
            const float* src = (kt < 2)
                ? (Wih_e + (size_t)gr * Fq + kc)
                : (Whh_e + (size_t)gr * Hq + (kc - 64));
            float4 f0 = *(const float4*)src;
            float4 f1 = *(const float4*)(src + 4);
            f16x8 a;
            a[0] = (f16)(f0.x * fg); a[1] = (f16)(f0.y * fg);
            a[2] = (f16)(f0.z * fg); a[3] = (f16)(f0.w * fg);
            a[4] = (f16)(f1.x * fg); a[5] = (f16)(f1.y * fg);
            a[6] = (f16)(f1.z * fg); a[7] = (f16)(f1.w * fg);
            wf[g][kt] = a;
        }
        f32x4 b1 = *(const f32x4*)(bih_e + g * 128 + wv * 16 + kg * 4);
        f32x4 b2 = *(const f32x4*)(bhh_e + g * 128 + wv * 16 + kg * 4);
        bias4[g] = (b1 + b2) * fg;
    }

    // zero h buffer 0
    if (act) {
        f16x4 z; z[0] = (f16)0.f; z[1] = (f16)0.f; z[2] = (f16)0.f; z[3] = (f16)0.f;
        *(f16x4*)(&hT[0][n16][wv * 16 + kg * 4]) = z;
    }
    // stage x chunk 0: thread -> (r, t8, fg)
    const int sr = tid >> 7, st8 = (tid >> 4) & 7, sfg = tid & 15;
    {
        float4 v = *(const float4*)(ts + (size_t)(row0 + sr) * Tq * Fq +
                                    (size_t)st8 * Fq + sfg * 4);
        f16x4 h4; h4[0] = (f16)v.x; h4[1] = (f16)v.y; h4[2] = (f16)v.z; h4[3] = (f16)v.w;
        *(f16x4*)(&xS[0][sr][st8][sfg * 4]) = h4;
    }
    __syncthreads();

    // prologue: group 0's x-partials (times 0..3, slots us of chunk 0)
#pragma unroll
    for (int g = 0; g < 4; ++g) {
        f16x8 bx0 = *(const f16x8*)(&xS[0][zr][us][kg * 8]);
        f16x8 bx1 = *(const f16x8*)(&xS[0][zr][us][32 + kg * 8]);
        f32x4 xacc = __builtin_amdgcn_mfma_f32_16x16x32_f16(wf[g][0], bx0, bias4[g], 0, 0, 0);
        xacc = __builtin_amdgcn_mfma_f32_16x16x32_f16(wf[g][1], bx1, xacc, 0, 0, 0);
        *(f32x4*)(&xg[0][wv][g][us][zr][kg * 4]) = xacc;
    }

    // ===================== encoder: 512 steps, 1 barrier each ============
    for (int tc = 0; tc < Tq; tc += 8) {
        float4 xpre;
        const int buf = (tc >> 3) & 1;
        if (tc < Tq - 8) {   // issue chunk+1 loads at chunk start
            xpre = *(const float4*)(ts + (size_t)(row0 + sr) * Tq * Fq +
                                    (size_t)(tc + 8 + st8) * Fq + sfg * 4);
        }
#pragma unroll
        for (int u = 0; u < 8; ++u) {
            const int t = tc + u;
            const int par = u & 1;       // compile-time
            const int dt = u & 3;        // compile-time
            const int cb = u >> 2;       // xg read buffer (compile-time)
            // spread x-pass: gate g=dt of the NEXT 4-group
            if (t < Tq - 4) {
                const int xb  = (u < 4) ? buf : (buf ^ 1);
                const int bs  = (u < 4) ? 4 : 0;           // slot base
                f16x8 bx0 = *(const f16x8*)(&xS[xb][zr][bs + us][kg * 8]);
                f16x8 bx1 = *(const f16x8*)(&xS[xb][zr][bs + us][32 + kg * 8]);
                f32x4 xacc = __builtin_amdgcn_mfma_f32_16x16x32_f16(
                    wf[dt][0], bx0, bias4[dt], 0, 0, 0);
                xacc = __builtin_amdgcn_mfma_f32_16x16x32_f16(
                    wf[dt][1], bx1, xacc, 0, 0, 0);
                *(f32x4*)(&xg[cb ^ 1][wv][dt][us][zr][kg * 4]) = xacc;
            }
            // C-init for this step from xg[cb] (wave-private, barrier-old)
            f32x4 acc[4];
#pragma unroll
            for (int g = 0; g < 4; ++g)
                acc[g] = *(const f32x4*)(&xg[cb][wv][g][dt][zr][kg * 4]);
            // h-part: 4 tiles
            f16x8 bh0 = *(const f16x8*)(&hT[par][zr][kg * 8]);
            f16x8 bh1 = *(const f16x8*)(&hT[par][zr][32 + kg * 8]);
            f16x8 bh2 = *(const f16x8*)(&hT[par][zr][64 + kg * 8]);
            f16x8 bh3 = *(const f16x8*)(&hT[par][zr][96 + kg * 8]);
#pragma unroll
            for (int g = 0; g < 4; ++g) {
                acc[g] = __builtin_amdgcn_mfma_f32_16x16x32_f16(wf[g][2], bh0, acc[g], 0, 0, 0);
                acc[g] = __builtin_amdgcn_mfma_f32_16x16x32_f16(wf[g][3], bh1, acc[g], 0, 0, 0);
                acc[g] = __builtin_amdgcn_mfma_f32_16x16x32_f16(wf[g][4], bh2, acc[g], 0, 0, 0);
                acc[g] = __builtin_amdgcn_mfma_f32_16x16x32_f16(wf[g][5], bh3, acc[g], 0, 0, 0);
            }
            {   // pointwise (exp2-domain, rcp)
                float gi = sel4(acc[0], us);
                float gf = sel4(acc[1], us);
                float gg = sel4(acc[2], us);
                float go = sel4(acc[3], us);
                float i_ = rcpf_(1.f + exp2f_(-gi));
                float f_ = rcpf_(1.f + exp2f_(-gf));
                float g_ = 1.f - 2.f * rcpf_(exp2f_(gg) + 1.f);
                float o_ = rcpf_(1.f + exp2f_(-go));
                c_ = f_ * c_ + i_ * g_;
                float th = 1.f - 2.f * rcpf_(exp2f_(c_ * TWO_LOG2E) + 1.f);
                hT[par ^ 1][zr][wv * 16 + un] = (f16)(o_ * th);
            }
            if (u == 3 && tc < Tq - 8) {   // publish next chunk (4-step slack)
                f16x4 h4; h4[0] = (f16)xpre.x; h4[1] = (f16)xpre.y;
                h4[2] = (f16)xpre.z; h4[3] = (f16)xpre.w;
                *(f16x4*)(&xS[buf ^ 1][sr][st8][sfg * 4]) = h4;
            }
            __syncthreads();
        }
    }

    // c_enc: thread owns unit wv*16+un of batch row zr
    out[(size_t)(row0 + zr) * Hq + wv * 16 + un] = c_;

    // ===================== decoder setup =====================
    f16x8 wc[4][4];   // folded (scaled) weights from ws: 16 x 16B loads
#pragma unroll
    for (int g = 0; g < 4; ++g) {
        const int gr = g * 128 + wv * 16 + n16;
#pragma unroll
        for (int kt = 0; kt < 4; ++kt)
            wc[g][kt] = *(const f16x8*)(Wcomb + (size_t)gr * Hq + kt * 32 + kg * 8);
        bias4[g] = *(const f32x4*)(bfold + g * 128 + wv * 16 + kg * 4);
    }
    // proj A-frags (waves 4..7 use them; mt=wv&3 keeps addresses valid)
    const int mt = wv & 3;
    f16x8 wo[4];
#pragma unroll
    for (int kt = 0; kt < 4; ++kt) {
        const float* src = Wout + (size_t)(mt * 16 + n16) * Hq + kt * 32 + kg * 8;
        float4 f0 = *(const float4*)src;
        float4 f1 = *(const float4*)(src + 4);
        f16x8 a;
        a[0] = (f16)f0.x; a[1] = (f16)f0.y; a[2] = (f16)f0.z; a[3] = (f16)f0.w;
        a[4] = (f16)f1.x; a[5] = (f16)f1.y; a[6] = (f16)f1.z; a[7] = (f16)f1.w;
        wo[kt] = a;
    }
    f32x4 bo4 = *(const f32x4*)(bout + mt * 16 + kg * 4);
    float4 tsv = *(const float4*)(ts + (size_t)(row0 + zr) * Tq * Fq +
                                  (size_t)(Tq - 1) * Fq + mt * 16 + kg * 4);
    float err_ = 0.f;
    __syncthreads();

    // ===================== decoder: 512 steps, 1 barrier each ============
    for (int k = 0; k < Tq; k += 2) {
#pragma unroll
        for (int u = 0; u < 2; ++u) {
            const int kk = k + u;
            const int pk = u;            // compile-time
            f16x8 bh0 = *(const f16x8*)(&hT[pk][zr][kg * 8]);
            f16x8 bh1 = *(const f16x8*)(&hT[pk][zr][32 + kg * 8]);
            f16x8 bh2 = *(const f16x8*)(&hT[pk][zr][64 + kg * 8]);
            f16x8 bh3 = *(const f16x8*)(&hT[pk][zr][96 + kg * 8]);
            f32x4 acc[4];
#pragma unroll
            for (int g = 0; g < 4; ++g) {
                acc[g] = __builtin_amdgcn_mfma_f32_16x16x32_f16(wc[g][0], bh0, bias4[g], 0, 0, 0);
                acc[g] = __builtin_amdgcn_mfma_f32_16x16x32_f16(wc[g][1], bh1, acc[g], 0, 0, 0);
                acc[g] = __builtin_amdgcn_mfma_f32_16x16x32_f16(wc[g][2], bh2, acc[g], 0, 0, 0);
                acc[g] = __builtin_amdgcn_mfma_f32_16x16x32_f16(wc[g][3], bh3, acc[g], 0, 0, 0);
            }
            if (wv >= 4) {   // concurrent projection of h[pk] for rec_err
                f32x4 pacc = __builtin_amdgcn_mfma_f32_16x16x32_f16(wo[0], bh0, bo4, 0, 0, 0);
                pacc = __builtin_amdgcn_mfma_f32_16x16x32_f16(wo[1], bh1, pacc, 0, 0, 0);
                pacc = __builtin_amdgcn_mfma_f32_16x16x32_f16(wo[2], bh2, pacc, 0, 0, 0);
                pacc = __builtin_amdgcn_mfma_f32_16x16x32_f16(wo[3], bh3, pacc, 0, 0, 0);
                if (act) {
                    float a0 = pacc[0], a1 = pacc[1], a2 = pacc[2], a3 = pacc[3];
                    if (kk == 0) {
                        float4 av; av.x = a0; av.y = a1; av.z = a2; av.w = a3;
                        *(float4*)(out + (size_t)Bq * Hq + Bq +
                                   (size_t)(row0 + n16) * Fq + mt * 16 + kg * 4) = av;
                    }
                    err_ += fabsf(a0 * a0 - tsv.x * tsv.x);
                    err_ += fabsf(a1 * a1 - tsv.y * tsv.y);
                    err_ += fabsf(a2 * a2 - tsv.z * tsv.z);
                    err_ += fabsf(a3 * a3 - tsv.w * tsv.w);
                    if (kk < Tq - 1)
                        tsv = *(const float4*)(ts + (size_t)(row0 + n16) * Tq * Fq +
                                               (size_t)(Tq - 2 - kk) * Fq +
                                               mt * 16 + kg * 4);
                }
            }
            {   // pointwise
                float gi = sel4(acc[0], us);
                float gf = sel4(acc[1], us);
                float gg = sel4(acc[2], us);
                float go = sel4(acc[3], us);
                float i_ = rcpf_(1.f + exp2f_(-gi));
                float f_ = rcpf_(1.f + exp2f_(-gf));
                float g_ = 1.f - 2.f * rcpf_(exp2f_(gg) + 1.f);
                float o_ = rcpf_(1.f + exp2f_(-go));
                c_ = f_ * c_ + i_ * g_;
                float th = 1.f - 2.f * rcpf_(exp2f_(c_ * TWO_LOG2E) + 1.f);
                hT[pk ^ 1][zr][wv * 16 + un] = (f16)(o_ * th);
            }
            __syncthreads();
        }
    }

    // rec_err reduction: waves 4..7 hold per-(row,f-slice) partials
    if (wv >= 4) {
        err_ += __shfl_xor(err_, 16, 64);   // sum over kg bit 0
        err_ += __shfl_xor(err_, 32, 64);   // sum over kg bit 1
        if (kg == 0 && act) errb[mt][n16] = err_;
    }
    __syncthreads();
    if (tid < 4) {
        float e = errb[0][tid] + errb[1][tid] + errb[2][tid] + errb[3][tid];
        out[(size_t)Bq * Hq + row0 + tid] = e;
    }
}

extern "C" void kernel_launch(void* const* d_in, const int* in_sizes, int n_in,
                              void* d_out, int out_size, void* d_ws, size_t ws_size,
                              hipStream_t stream) {
    const float* ts    = (const float*)d_in[0];
    const float* Wih_e = (const float*)d_in[1];
    const float* Whh_e = (const float*)d_in[2];
    const float* bih_e = (const float*)d_in[3];
    const float* bhh_e = (const float*)d_in[4];
    const float* Wih_d = (const float*)d_in[5];
    const float* Whh_d = (const float*)d_in[6];
    const float* bih_d = (const float*)d_in[7];
    const float* bhh_d = (const float*)d_in[8];
    const float* Wout  = (const float*)d_in[9];
    const float* bout  = (const float*)d_in[10];
    float* out = (float*)d_out;

    f16*   Wcomb = (f16*)d_ws;                                   // 128 KB
    float* bfold = (float*)((char*)d_ws + (size_t)512 * 128 * 2); // +2 KB

    hipLaunchKernelGGL(fold_kernel, dim3(128), dim3(256), 0, stream,
                       Wih_d, Whh_d, bih_d, bhh_d, Wout, bout, Wcomb, bfold);
    hipLaunchKernelGGL(lstm_ae_kernel, dim3(Bq / 4), dim3(512), 0, stream,
                       ts, Wih_e, Whh_e, bih_e, bhh_e,
                       Wout, bout, Wcomb, bfold, out);
}

// Round 17
// 617.653 us; speedup vs baseline: 1.0664x; 1.0664x over previous
//
#include <hip/hip_runtime.h>

// Problem constants
#define Bq 1024
#define Tq 512
#define Fq 64    // input features
#define Hq 128   // hidden
#define LOG2E 1.44269504089f
#define TWO_LOG2E 2.88539008177f

typedef _Float16 f16;
typedef f16 f16x2 __attribute__((ext_vector_type(2)));
typedef f16 f16x4 __attribute__((ext_vector_type(4)));
typedef f16 f16x8 __attribute__((ext_vector_type(8)));
typedef float f32x4 __attribute__((ext_vector_type(4)));

__device__ __forceinline__ float exp2f_(float x) {
#if __has_builtin(__builtin_amdgcn_exp2f)
    return __builtin_amdgcn_exp2f(x);
#else
    return __expf(x * 0.69314718056f);
#endif
}
__device__ __forceinline__ float rcpf_(float x) {
#if __has_builtin(__builtin_amdgcn_rcpf)
    return __builtin_amdgcn_rcpf(x);
#else
    return 1.f / x;
#endif
}

// compile-time-indexed select of one element of an f32x4 (3 cndmasks)
__device__ __forceinline__ float sel4(f32x4 v, int s) {
    float r = v.x;
    r = (s == 1) ? v.y : r;
    r = (s == 2) ? v.z : r;
    r = (s == 3) ? v.w : r;
    return r;
}

// ---------------- kernel A: decoder fold (one-time, tiny) ----------------
// W_comb = (W_ih_dec @ W_out + W_hh_dec) * lg  (f16, [512][128])
// b_fold = (b_ih+b_hh+W_ih_dec@b_out) * lg     (f32, [512])
// lg = log2e for i,f,o gates; 2*log2e for the g gate (exp2-based pointwise).
__global__ __launch_bounds__(256) void fold_kernel(
    const float* __restrict__ Wih_d, const float* __restrict__ Whh_d,
    const float* __restrict__ bih_d, const float* __restrict__ bhh_d,
    const float* __restrict__ Wout, const float* __restrict__ bout,
    f16* __restrict__ Wcomb, float* __restrict__ bfold)
{
    const int gid = blockIdx.x * 256 + threadIdx.x;   // 0..32767
    const int og = gid >> 6;          // gate row 0..511
    const int oh = (gid & 63) * 2;    // hh pair
    const float lg = ((og >> 7) == 2) ? TWO_LOG2E : LOG2E;
    float ax = Whh_d[(size_t)og * Hq + oh];
    float ay = Whh_d[(size_t)og * Hq + oh + 1];
    for (int f = 0; f < Fq; ++f) {
        float w = Wih_d[(size_t)og * Fq + f];
        float2 o = *(const float2*)(Wout + (size_t)f * Hq + oh);
        ax += w * o.x; ay += w * o.y;
    }
    f16x2 r; r.x = (f16)(ax * lg); r.y = (f16)(ay * lg);
    *(f16x2*)(Wcomb + (size_t)og * Hq + oh) = r;
    if (gid < 512) {
        const float lgb = ((gid >> 7) == 2) ? TWO_LOG2E : LOG2E;
        float b = bih_d[gid] + bhh_d[gid];
        for (int f = 0; f < Fq; ++f)
            b += Wih_d[(size_t)gid * Fq + f] * bout[f];
        bfold[gid] = b * lgb;
    }
}

// ---------------- kernel B: main recurrence ----------------
// 256 blocks x 512 threads (8 waves), 4 batch rows, 1 block/CU.
// EXACTLY r15 (604us: exp2/rcp pointwise with log2e folded into weights,
// 4-step x-batch into single xg, bias C-init, folded decoder, 1
// barrier/step) with ONE isolated change: encoder unrolled x8 / decoder
// x2 so tb/buf/par/dt/pk are compile-time -> imm-offset ds_reads, no
// exec-mask churn, minimal address VALU. (r16 showed the unroll cuts
// VALU; its regression came from the xg[2] every-step write pattern,
// which is NOT repeated here.)
// Frag layouts (validated r4-r16):
//   A: lane l holds A[l&15][(l>>4)*8+j]   B: lane l holds B[(l>>4)*8+j][l&15]
//   D: lane l reg r = D[(l>>4)*4+r][l&15]
__global__ __launch_bounds__(512)
__attribute__((amdgpu_waves_per_eu(2)))
void lstm_ae_kernel(
    const float* __restrict__ ts,
    const float* __restrict__ Wih_e, const float* __restrict__ Whh_e,
    const float* __restrict__ bih_e, const float* __restrict__ bhh_e,
    const float* __restrict__ Wout, const float* __restrict__ bout,
    const f16* __restrict__ Wcomb, const float* __restrict__ bfold,
    float* __restrict__ out)
{
    const int tid = threadIdx.x;
    const int bid = blockIdx.x;
    const int row0 = bid * 4;

    const int wv = tid >> 6;       // wave 0..7 (owns units wv*16..wv*16+15)
    const int ln = tid & 63;
    const int n16 = ln & 15;       // MFMA N col
    const int kg = ln >> 4;        // k-group 0..3 (D rows kg*4..kg*4+3)
    const int zr = n16 & 3;        // batch row for B-frag AND pointwise col
    const bool act = (n16 < 4);
    const int us = n16 >> 2;       // D-reg select / x-pass time offset
    const int un = kg * 4 + us;    // pointwise: unit (wv*16+un), col zr

    __shared__ alignas(16) f16 hT[2][4][144];          // h dbuf
    __shared__ alignas(16) f16 xS[2][4][8][76];        // x chunk dbuf
    __shared__ alignas(16) float xg[8][4][4][4][16];   // x-partial bounce 32KB
    __shared__ float errb[4][4];

    float c_ = 0.f;     // one unit (wv*16+un), one batch col (zr)
    f32x4 bias4[4];     // scaled bias, C-init of the x-pass / decoder chain

    // ===================== encoder setup =====================
    f16x8 wf[4][6];   // A-frags [gate][k-tile], 96 VGPR (log2e-scaled)
#pragma unroll
    for (int g = 0; g < 4; ++g) {
        const float fg = (g == 2) ? TWO_LOG2E : LOG2E;
        const int gr = g * 128 + wv * 16 + n16;
#pragma unroll
        for (int kt = 0; kt < 6; ++kt) {
            const int kc = kt * 32 + kg * 8;
            const float* src = (kt < 2)
                ? (Wih_e + (size_t)gr * Fq + kc)
                : (Whh_e + (size_t)gr * Hq + (kc - 64));
            float4 f0 = *(const float4*)src;
            float4 f1 = *(const float4*)(src + 4);
            f16x8 a;
            a[0] = (f16)(f0.x * fg); a[1] = (f16)(f0.y * fg);
            a[2] = (f16)(f0.z * fg); a[3] = (f16)(f0.w * fg);
            a[4] = (f16)(f1.x * fg); a[5] = (f16)(f1.y * fg);
            a[6] = (f16)(f1.z * fg); a[7] = (f16)(f1.w * fg);
            wf[g][kt] = a;
        }
        f32x4 b1 = *(const f32x4*)(bih_e + g * 128 + wv * 16 + kg * 4);
        f32x4 b2 = *(const f32x4*)(bhh_e + g * 128 + wv * 16 + kg * 4);
        bias4[g] = (b1 + b2) * fg;
    }

    // zero h buffer 0
    if (act) {
        f16x4 z; z[0] = (f16)0.f; z[1] = (f16)0.f; z[2] = (f16)0.f; z[3] = (f16)0.f;
        *(f16x4*)(&hT[0][n16][wv * 16 + kg * 4]) = z;
    }
    // stage x chunk 0: thread -> (r, t8, fg)
    const int sr = tid >> 7, st8 = (tid >> 4) & 7, sfg = tid & 15;
    {
        float4 v = *(const float4*)(ts + (size_t)(row0 + sr) * Tq * Fq +
                                    (size_t)st8 * Fq + sfg * 4);
        f16x4 h4; h4[0] = (f16)v.x; h4[1] = (f16)v.y; h4[2] = (f16)v.z; h4[3] = (f16)v.w;
        *(f16x4*)(&xS[0][sr][st8][sfg * 4]) = h4;
    }
    __syncthreads();

    // ===================== encoder: 512 steps, 1 barrier each ============
    for (int tc = 0; tc < Tq; tc += 8) {
        const int buf = (tc >> 3) & 1;
        float4 xpre;
#pragma unroll
        for (int u = 0; u < 8; ++u) {
            const int t = tc + u;
            const int par = u & 1;       // compile-time
            const int dt = u & 3;        // compile-time
            if (u == 0 && tc < Tq - 8) { // issue chunk+1 loads
                xpre = *(const float4*)(ts + (size_t)(row0 + sr) * Tq * Fq +
                                        (size_t)(tc + 8 + st8) * Fq + sfg * 4);
            }
            if (dt == 0) {   // x-burst: times t..t+3 across the 16 N-cols
                f16x8 bx0 = *(const f16x8*)(&xS[buf][zr][u + us][kg * 8]);
                f16x8 bx1 = *(const f16x8*)(&xS[buf][zr][u + us][32 + kg * 8]);
#pragma unroll
                for (int g = 0; g < 4; ++g) {
                    f32x4 xacc = __builtin_amdgcn_mfma_f32_16x16x32_f16(
                        wf[g][0], bx0, bias4[g], 0, 0, 0);
                    xacc = __builtin_amdgcn_mfma_f32_16x16x32_f16(
                        wf[g][1], bx1, xacc, 0, 0, 0);
                    *(f32x4*)(&xg[wv][g][us][zr][kg * 4]) = xacc;
                }
            }
            // C-init for this step from xg (wave-private)
            f32x4 acc[4];
#pragma unroll
            for (int g = 0; g < 4; ++g)
                acc[g] = *(const f32x4*)(&xg[wv][g][dt][zr][kg * 4]);
            // h-part: 4 tiles (imm-offset ds_reads, par compile-time)
            f16x8 bh0 = *(const f16x8*)(&hT[par][zr][kg * 8]);
            f16x8 bh1 = *(const f16x8*)(&hT[par][zr][32 + kg * 8]);
            f16x8 bh2 = *(const f16x8*)(&hT[par][zr][64 + kg * 8]);
            f16x8 bh3 = *(const f16x8*)(&hT[par][zr][96 + kg * 8]);
#pragma unroll
            for (int g = 0; g < 4; ++g) {
                acc[g] = __builtin_amdgcn_mfma_f32_16x16x32_f16(wf[g][2], bh0, acc[g], 0, 0, 0);
                acc[g] = __builtin_amdgcn_mfma_f32_16x16x32_f16(wf[g][3], bh1, acc[g], 0, 0, 0);
                acc[g] = __builtin_amdgcn_mfma_f32_16x16x32_f16(wf[g][4], bh2, acc[g], 0, 0, 0);
                acc[g] = __builtin_amdgcn_mfma_f32_16x16x32_f16(wf[g][5], bh3, acc[g], 0, 0, 0);
            }
            {   // pointwise (exp2-domain, rcp)
                float gi = sel4(acc[0], us);
                float gf = sel4(acc[1], us);
                float gg = sel4(acc[2], us);
                float go = sel4(acc[3], us);
                float i_ = rcpf_(1.f + exp2f_(-gi));
                float f_ = rcpf_(1.f + exp2f_(-gf));
                float g_ = 1.f - 2.f * rcpf_(exp2f_(gg) + 1.f);
                float o_ = rcpf_(1.f + exp2f_(-go));
                c_ = f_ * c_ + i_ * g_;
                float th = 1.f - 2.f * rcpf_(exp2f_(c_ * TWO_LOG2E) + 1.f);
                hT[par ^ 1][zr][wv * 16 + un] = (f16)(o_ * th);
            }
            if (u == 7 && tc < Tq - 8) {   // publish staged chunk
                f16x4 h4; h4[0] = (f16)xpre.x; h4[1] = (f16)xpre.y;
                h4[2] = (f16)xpre.z; h4[3] = (f16)xpre.w;
                *(f16x4*)(&xS[buf ^ 1][sr][st8][sfg * 4]) = h4;
            }
            __syncthreads();
        }
    }

    // c_enc: thread owns unit wv*16+un of batch row zr
    out[(size_t)(row0 + zr) * Hq + wv * 16 + un] = c_;

    // ===================== decoder setup =====================
    f16x8 wc[4][4];   // folded (scaled) weights from ws: 16 x 16B loads
#pragma unroll
    for (int g = 0; g < 4; ++g) {
        const int gr = g * 128 + wv * 16 + n16;
#pragma unroll
        for (int kt = 0; kt < 4; ++kt)
            wc[g][kt] = *(const f16x8*)(Wcomb + (size_t)gr * Hq + kt * 32 + kg * 8);
        bias4[g] = *(const f32x4*)(bfold + g * 128 + wv * 16 + kg * 4);
    }
    // proj A-frags (waves 4..7 use them; mt=wv&3 keeps addresses valid)
    const int mt = wv & 3;
    f16x8 wo[4];
#pragma unroll
    for (int kt = 0; kt < 4; ++kt) {
        const float* src = Wout + (size_t)(mt * 16 + n16) * Hq + kt * 32 + kg * 8;
        float4 f0 = *(const float4*)src;
        float4 f1 = *(const float4*)(src + 4);
        f16x8 a;
        a[0] = (f16)f0.x; a[1] = (f16)f0.y; a[2] = (f16)f0.z; a[3] = (f16)f0.w;
        a[4] = (f16)f1.x; a[5] = (f16)f1.y; a[6] = (f16)f1.z; a[7] = (f16)f1.w;
        wo[kt] = a;
    }
    f32x4 bo4 = *(const f32x4*)(bout + mt * 16 + kg * 4);
    float4 tsv = *(const float4*)(ts + (size_t)(row0 + zr) * Tq * Fq +
                                  (size_t)(Tq - 1) * Fq + mt * 16 + kg * 4);
    float err_ = 0.f;
    __syncthreads();

    // ===================== decoder: 512 steps, 1 barrier each ============
    for (int k = 0; k < Tq; k += 2) {
#pragma unroll
        for (int u = 0; u < 2; ++u) {
            const int kk = k + u;
            const int pk = u;            // compile-time
            f16x8 bh0 = *(const f16x8*)(&hT[pk][zr][kg * 8]);
            f16x8 bh1 = *(const f16x8*)(&hT[pk][zr][32 + kg * 8]);
            f16x8 bh2 = *(const f16x8*)(&hT[pk][zr][64 + kg * 8]);
            f16x8 bh3 = *(const f16x8*)(&hT[pk][zr][96 + kg * 8]);
            f32x4 acc[4];
#pragma unroll
            for (int g = 0; g < 4; ++g) {
                acc[g] = __builtin_amdgcn_mfma_f32_16x16x32_f16(wc[g][0], bh0, bias4[g], 0, 0, 0);
                acc[g] = __builtin_amdgcn_mfma_f32_16x16x32_f16(wc[g][1], bh1, acc[g], 0, 0, 0);
                acc[g] = __builtin_amdgcn_mfma_f32_16x16x32_f16(wc[g][2], bh2, acc[g], 0, 0, 0);
                acc[g] = __builtin_amdgcn_mfma_f32_16x16x32_f16(wc[g][3], bh3, acc[g], 0, 0, 0);
            }
            if (wv >= 4) {   // concurrent projection of h[pk] for rec_err
                f32x4 pacc = __builtin_amdgcn_mfma_f32_16x16x32_f16(wo[0], bh0, bo4, 0, 0, 0);
                pacc = __builtin_amdgcn_mfma_f32_16x16x32_f16(wo[1], bh1, pacc, 0, 0, 0);
                pacc = __builtin_amdgcn_mfma_f32_16x16x32_f16(wo[2], bh2, pacc, 0, 0, 0);
                pacc = __builtin_amdgcn_mfma_f32_16x16x32_f16(wo[3], bh3, pacc, 0, 0, 0);
                if (act) {
                    float a0 = pacc[0], a1 = pacc[1], a2 = pacc[2], a3 = pacc[3];
                    if (kk == 0) {
                        float4 av; av.x = a0; av.y = a1; av.z = a2; av.w = a3;
                        *(float4*)(out + (size_t)Bq * Hq + Bq +
                                   (size_t)(row0 + n16) * Fq + mt * 16 + kg * 4) = av;
                    }
                    err_ += fabsf(a0 * a0 - tsv.x * tsv.x);
                    err_ += fabsf(a1 * a1 - tsv.y * tsv.y);
                    err_ += fabsf(a2 * a2 - tsv.z * tsv.z);
                    err_ += fabsf(a3 * a3 - tsv.w * tsv.w);
                    if (kk < Tq - 1)
                        tsv = *(const float4*)(ts + (size_t)(row0 + n16) * Tq * Fq +
                                               (size_t)(Tq - 2 - kk) * Fq +
                                               mt * 16 + kg * 4);
                }
            }
            {   // pointwise
                float gi = sel4(acc[0], us);
                float gf = sel4(acc[1], us);
                float gg = sel4(acc[2], us);
                float go = sel4(acc[3], us);
                float i_ = rcpf_(1.f + exp2f_(-gi));
                float f_ = rcpf_(1.f + exp2f_(-gf));
                float g_ = 1.f - 2.f * rcpf_(exp2f_(gg) + 1.f);
                float o_ = rcpf_(1.f + exp2f_(-go));
                c_ = f_ * c_ + i_ * g_;
                float th = 1.f - 2.f * rcpf_(exp2f_(c_ * TWO_LOG2E) + 1.f);
                hT[pk ^ 1][zr][wv * 16 + un] = (f16)(o_ * th);
            }
            __syncthreads();
        }
    }

    // rec_err reduction: waves 4..7 hold per-(row,f-slice) partials
    if (wv >= 4) {
        err_ += __shfl_xor(err_, 16, 64);   // sum over kg bit 0
        err_ += __shfl_xor(err_, 32, 64);   // sum over kg bit 1
        if (kg == 0 && act) errb[mt][n16] = err_;
    }
    __syncthreads();
    if (tid < 4) {
        float e = errb[0][tid] + errb[1][tid] + errb[2][tid] + errb[3][tid];
        out[(size_t)Bq * Hq + row0 + tid] = e;
    }
}

extern "C" void kernel_launch(void* const* d_in, const int* in_sizes, int n_in,
                              void* d_out, int out_size, void* d_ws, size_t ws_size,
                              hipStream_t stream) {
    const float* ts    = (const float*)d_in[0];
    const float* Wih_e = (const float*)d_in[1];
    const float* Whh_e = (const float*)d_in[2];
    const float* bih_e = (const float*)d_in[3];
    const float* bhh_e = (const float*)d_in[4];
    const float* Wih_d = (const float*)d_in[5];
    const float* Whh_d = (const float*)d_in[6];
    const float* bih_d = (const float*)d_in[7];
    const float* bhh_d = (const float*)d_in[8];
    const float* Wout  = (const float*)d_in[9];
    const float* bout  = (const float*)d_in[10];
    float* out = (float*)d_out;

    f16*   Wcomb = (f16*)d_ws;                                   // 128 KB
    float* bfold = (float*)((char*)d_ws + (size_t)512 * 128 * 2); // +2 KB

    hipLaunchKernelGGL(fold_kernel, dim3(128), dim3(256), 0, stream,
                       Wih_d, Whh_d, bih_d, bhh_d, Wout, bout, Wcomb, bfold);
    hipLaunchKernelGGL(lstm_ae_kernel, dim3(Bq / 4), dim3(512), 0, stream,
                       ts, Wih_e, Whh_e, bih_e, bhh_e,
                       Wout, bout, Wcomb, bfold, out);
}

// Round 18
// 592.580 us; speedup vs baseline: 1.1115x; 1.0423x over previous
//
#include <hip/hip_runtime.h>

// Problem constants
#define Bq 1024
#define Tq 512
#define Fq 64    // input features
#define Hq 128   // hidden
#define LOG2E 1.44269504089f
#define TWO_LOG2E 2.88539008177f

typedef _Float16 f16;
typedef f16 f16x2 __attribute__((ext_vector_type(2)));
typedef f16 f16x4 __attribute__((ext_vector_type(4)));
typedef f16 f16x8 __attribute__((ext_vector_type(8)));
typedef float f32x4 __attribute__((ext_vector_type(4)));

__device__ __forceinline__ float exp2f_(float x) {
#if __has_builtin(__builtin_amdgcn_exp2f)
    return __builtin_amdgcn_exp2f(x);
#else
    return __expf(x * 0.69314718056f);
#endif
}
__device__ __forceinline__ float rcpf_(float x) {
#if __has_builtin(__builtin_amdgcn_rcpf)
    return __builtin_amdgcn_rcpf(x);
#else
    return 1.f / x;
#endif
}

// compile-time-indexed select of one element of an f32x4 (3 cndmasks)
__device__ __forceinline__ float sel4(f32x4 v, int s) {
    float r = v.x;
    r = (s == 1) ? v.y : r;
    r = (s == 2) ? v.z : r;
    r = (s == 3) ? v.w : r;
    return r;
}

// ---------------- kernel A: decoder fold (one-time, tiny) ----------------
// W_comb = (W_ih_dec @ W_out + W_hh_dec) * lg  (f16, [512][128])
// b_fold = (b_ih+b_hh+W_ih_dec@b_out) * lg     (f32, [512])
// lg = log2e for i,f,o gates; 2*log2e for the g gate (exp2-based pointwise).
__global__ __launch_bounds__(256) void fold_kernel(
    const float* __restrict__ Wih_d, const float* __restrict__ Whh_d,
    const float* __restrict__ bih_d, const float* __restrict__ bhh_d,
    const float* __restrict__ Wout, const float* __restrict__ bout,
    f16* __restrict__ Wcomb, float* __restrict__ bfold)
{
    const int gid = blockIdx.x * 256 + threadIdx.x;   // 0..32767
    const int og = gid >> 6;          // gate row 0..511
    const int oh = (gid & 63) * 2;    // hh pair
    const float lg = ((og >> 7) == 2) ? TWO_LOG2E : LOG2E;
    float ax = Whh_d[(size_t)og * Hq + oh];
    float ay = Whh_d[(size_t)og * Hq + oh + 1];
    for (int f = 0; f < Fq; ++f) {
        float w = Wih_d[(size_t)og * Fq + f];
        float2 o = *(const float2*)(Wout + (size_t)f * Hq + oh);
        ax += w * o.x; ay += w * o.y;
    }
    f16x2 r; r.x = (f16)(ax * lg); r.y = (f16)(ay * lg);
    *(f16x2*)(Wcomb + (size_t)og * Hq + oh) = r;
    if (gid < 512) {
        const float lgb = ((gid >> 7) == 2) ? TWO_LOG2E : LOG2E;
        float b = bih_d[gid] + bhh_d[gid];
        for (int f = 0; f < Fq; ++f)
            b += Wih_d[(size_t)gid * Fq + f] * bout[f];
        bfold[gid] = b * lgb;
    }
}

// ---------------- kernel B: main recurrence ----------------
// 256 blocks x 512 threads (8 waves), 4 batch rows, 1 block/CU.
// EXACTLY r15 (604us best: exp2/rcp pointwise with log2e folded into
// weights, 4-step x-batch, bias C-init, folded decoder, 1 barrier/step,
// rolled loop — r17 showed unrolling is neutral) with ONE change:
// xg layout [wv][g][us][ZR][KG*4] -> [wv][g][us][KG][ZR*4+r].
// Old layout: us-stride 64 === 0 mod 32 banks, so the b128 burst-write's
// 8-lane phases collided 4-8-way on (zr,kg) banks (conflicts 1.7e7->2.9e7
// when xg was added in r15). New layout: bank = (kg*16+zr*4) mod 32 ->
// consecutive lanes walk distinct bank-quads, max 2-way (free, m136).
// Read keeps 4-lane broadcast + 2-way. Pure layout change.
// Frag layouts (validated r4-r17):
//   A: lane l holds A[l&15][(l>>4)*8+j]   B: lane l holds B[(l>>4)*8+j][l&15]
//   D: lane l reg r = D[(l>>4)*4+r][l&15]
__global__ __launch_bounds__(512)
__attribute__((amdgpu_waves_per_eu(2)))
void lstm_ae_kernel(
    const float* __restrict__ ts,
    const float* __restrict__ Wih_e, const float* __restrict__ Whh_e,
    const float* __restrict__ bih_e, const float* __restrict__ bhh_e,
    const float* __restrict__ Wout, const float* __restrict__ bout,
    const f16* __restrict__ Wcomb, const float* __restrict__ bfold,
    float* __restrict__ out)
{
    const int tid = threadIdx.x;
    const int bid = blockIdx.x;
    const int row0 = bid * 4;

    const int wv = tid >> 6;       // wave 0..7 (owns units wv*16..wv*16+15)
    const int ln = tid & 63;
    const int n16 = ln & 15;       // MFMA N col
    const int kg = ln >> 4;        // k-group 0..3 (D rows kg*4..kg*4+3)
    const int zr = n16 & 3;        // batch row for B-frag AND pointwise col
    const bool act = (n16 < 4);
    const int us = n16 >> 2;       // D-reg select / x-pass time offset
    const int un = kg * 4 + us;    // pointwise: unit (wv*16+un), col zr

    __shared__ alignas(16) f16 hT[2][4][144];          // h dbuf
    __shared__ alignas(16) f16 xS[2][4][8][76];        // x chunk dbuf
    __shared__ alignas(16) float xg[8][4][4][4][16];   // [wv][g][us][kg][zr*4+r]
    __shared__ float errb[4][4];

    float c_ = 0.f;     // one unit (wv*16+un), one batch col (zr)
    f32x4 bias4[4];     // scaled bias, C-init of the x-pass / decoder chain

    // ===================== encoder setup =====================
    f16x8 wf[4][6];   // A-frags [gate][k-tile], 96 VGPR (log2e-scaled)
#pragma unroll
    for (int g = 0; g < 4; ++g) {
        const float fg = (g == 2) ? TWO_LOG2E : LOG2E;
        const int gr = g * 128 + wv * 16 + n16;
#pragma unroll
        for (int kt = 0; kt < 6; ++kt) {
            const int kc = kt * 32 + kg * 8;
            const float* src = (kt < 2)
                ? (Wih_e + (size_t)gr * Fq + kc)
                : (Whh_e + (size_t)gr * Hq + (kc - 64));
            float4 f0 = *(const float4*)src;
            float4 f1 = *(const float4*)(src + 4);
            f16x8 a;
            a[0] = (f16)(f0.x * fg); a[1] = (f16)(f0.y * fg);
            a[2] = (f16)(f0.z * fg); a[3] = (f16)(f0.w * fg);
            a[4] = (f16)(f1.x * fg); a[5] = (f16)(f1.y * fg);
            a[6] = (f16)(f1.z * fg); a[7] = (f16)(f1.w * fg);
            wf[g][kt] = a;
        }
        f32x4 b1 = *(const f32x4*)(bih_e + g * 128 + wv * 16 + kg * 4);
        f32x4 b2 = *(const f32x4*)(bhh_e + g * 128 + wv * 16 + kg * 4);
        bias4[g] = (b1 + b2) * fg;
    }

    // zero h buffer 0
    if (act) {
        f16x4 z; z[0] = (f16)0.f; z[1] = (f16)0.f; z[2] = (f16)0.f; z[3] = (f16)0.f;
        *(f16x4*)(&hT[0][n16][wv * 16 + kg * 4]) = z;
    }
    // stage x chunk 0: thread -> (r, t8, fg)
    const int sr = tid >> 7, st8 = (tid >> 4) & 7, sfg = tid & 15;
    {
        float4 v = *(const float4*)(ts + (size_t)(row0 + sr) * Tq * Fq +
                                    (size_t)st8 * Fq + sfg * 4);
        f16x4 h4; h4[0] = (f16)v.x; h4[1] = (f16)v.y; h4[2] = (f16)v.z; h4[3] = (f16)v.w;
        *(f16x4*)(&xS[0][sr][st8][sfg * 4]) = h4;
    }
    __syncthreads();

    // ===================== encoder: 512 steps, 1 barrier each ============
    float4 xpre;
    f32x4 xacc[4];
    for (int t = 0; t < Tq; ++t) {
        const int buf = (t >> 3) & 1, tb = t & 7, par = t & 1, dt = t & 3;
        if (tb == 0 && t < Tq - 8) {   // issue chunk c+1 loads (8 steps slack)
            xpre = *(const float4*)(ts + (size_t)(row0 + sr) * Tq * Fq +
                                    (size_t)(t + 8 + st8) * Fq + sfg * 4);
        }
        if (dt == 0) {   // x-pass: 4 steps' x-partials across the 16 N-cols
            const int xt = tb + us;          // this col carries time t+us
            f16x8 bx0 = *(const f16x8*)(&xS[buf][zr][xt][kg * 8]);
            f16x8 bx1 = *(const f16x8*)(&xS[buf][zr][xt][32 + kg * 8]);
#pragma unroll
            for (int g = 0; g < 4; ++g) {
                xacc[g] = __builtin_amdgcn_mfma_f32_16x16x32_f16(
                    wf[g][0], bx0, bias4[g], 0, 0, 0);
                xacc[g] = __builtin_amdgcn_mfma_f32_16x16x32_f16(
                    wf[g][1], bx1, xacc[g], 0, 0, 0);
                *(f32x4*)(&xg[wv][g][us][kg][zr * 4]) = xacc[g];
            }
        }
        // C-init for this step from the wave-private bounce (col-redistribute)
        f32x4 acc[4];
#pragma unroll
        for (int g = 0; g < 4; ++g)
            acc[g] = *(const f32x4*)(&xg[wv][g][dt][kg][zr * 4]);
        // h-part: 4 tiles
        f16x8 bh0 = *(const f16x8*)(&hT[par][zr][kg * 8]);
        f16x8 bh1 = *(const f16x8*)(&hT[par][zr][32 + kg * 8]);
        f16x8 bh2 = *(const f16x8*)(&hT[par][zr][64 + kg * 8]);
        f16x8 bh3 = *(const f16x8*)(&hT[par][zr][96 + kg * 8]);
#pragma unroll
        for (int g = 0; g < 4; ++g) {
            acc[g] = __builtin_amdgcn_mfma_f32_16x16x32_f16(wf[g][2], bh0, acc[g], 0, 0, 0);
            acc[g] = __builtin_amdgcn_mfma_f32_16x16x32_f16(wf[g][3], bh1, acc[g], 0, 0, 0);
            acc[g] = __builtin_amdgcn_mfma_f32_16x16x32_f16(wf[g][4], bh2, acc[g], 0, 0, 0);
            acc[g] = __builtin_amdgcn_mfma_f32_16x16x32_f16(wf[g][5], bh3, acc[g], 0, 0, 0);
        }
        {   // pointwise (exp2-domain gates, rcp instead of divide)
            float gi = sel4(acc[0], us);
            float gf = sel4(acc[1], us);
            float gg = sel4(acc[2], us);
            float go = sel4(acc[3], us);
            float i_ = rcpf_(1.f + exp2f_(-gi));
            float f_ = rcpf_(1.f + exp2f_(-gf));
            float g_ = 1.f - 2.f * rcpf_(exp2f_(gg) + 1.f);
            float o_ = rcpf_(1.f + exp2f_(-go));
            c_ = f_ * c_ + i_ * g_;
            float th = 1.f - 2.f * rcpf_(exp2f_(c_ * TWO_LOG2E) + 1.f);
            hT[par ^ 1][zr][wv * 16 + un] = (f16)(o_ * th);
        }
        if (tb == 7 && t != Tq - 1) {  // publish staged chunk
            f16x4 h4; h4[0] = (f16)xpre.x; h4[1] = (f16)xpre.y;
            h4[2] = (f16)xpre.z; h4[3] = (f16)xpre.w;
            *(f16x4*)(&xS[buf ^ 1][sr][st8][sfg * 4]) = h4;
        }
        __syncthreads();
    }

    // c_enc: thread owns unit wv*16+un of batch row zr
    out[(size_t)(row0 + zr) * Hq + wv * 16 + un] = c_;

    // ===================== decoder setup =====================
    f16x8 wc[4][4];   // folded (scaled) weights from ws: 16 x 16B loads
#pragma unroll
    for (int g = 0; g < 4; ++g) {
        const int gr = g * 128 + wv * 16 + n16;
#pragma unroll
        for (int kt = 0; kt < 4; ++kt)
            wc[g][kt] = *(const f16x8*)(Wcomb + (size_t)gr * Hq + kt * 32 + kg * 8);
        bias4[g] = *(const f32x4*)(bfold + g * 128 + wv * 16 + kg * 4);
    }
    // proj A-frags (waves 4..7 use them; mt=wv&3 keeps addresses valid)
    const int mt = wv & 3;
    f16x8 wo[4];
#pragma unroll
    for (int kt = 0; kt < 4; ++kt) {
        const float* src = Wout + (size_t)(mt * 16 + n16) * Hq + kt * 32 + kg * 8;
        float4 f0 = *(const float4*)src;
        float4 f1 = *(const float4*)(src + 4);
        f16x8 a;
        a[0] = (f16)f0.x; a[1] = (f16)f0.y; a[2] = (f16)f0.z; a[3] = (f16)f0.w;
        a[4] = (f16)f1.x; a[5] = (f16)f1.y; a[6] = (f16)f1.z; a[7] = (f16)f1.w;
        wo[kt] = a;
    }
    f32x4 bo4 = *(const f32x4*)(bout + mt * 16 + kg * 4);
    float4 tsv = *(const float4*)(ts + (size_t)(row0 + zr) * Tq * Fq +
                                  (size_t)(Tq - 1) * Fq + mt * 16 + kg * 4);
    float err_ = 0.f;
    __syncthreads();

    // ===================== decoder: 512 steps, 1 barrier each ============
    for (int k = 0; k < Tq; ++k) {
        const int pk = k & 1;
        f16x8 bh0 = *(const f16x8*)(&hT[pk][zr][kg * 8]);
        f16x8 bh1 = *(const f16x8*)(&hT[pk][zr][32 + kg * 8]);
        f16x8 bh2 = *(const f16x8*)(&hT[pk][zr][64 + kg * 8]);
        f16x8 bh3 = *(const f16x8*)(&hT[pk][zr][96 + kg * 8]);
        f32x4 acc[4];
#pragma unroll
        for (int g = 0; g < 4; ++g) {
            acc[g] = __builtin_amdgcn_mfma_f32_16x16x32_f16(wc[g][0], bh0, bias4[g], 0, 0, 0);
            acc[g] = __builtin_amdgcn_mfma_f32_16x16x32_f16(wc[g][1], bh1, acc[g], 0, 0, 0);
            acc[g] = __builtin_amdgcn_mfma_f32_16x16x32_f16(wc[g][2], bh2, acc[g], 0, 0, 0);
            acc[g] = __builtin_amdgcn_mfma_f32_16x16x32_f16(wc[g][3], bh3, acc[g], 0, 0, 0);
        }
        if (wv >= 4) {   // concurrent projection of h[pk] for rec_err
            f32x4 pacc = __builtin_amdgcn_mfma_f32_16x16x32_f16(wo[0], bh0, bo4, 0, 0, 0);
            pacc = __builtin_amdgcn_mfma_f32_16x16x32_f16(wo[1], bh1, pacc, 0, 0, 0);
            pacc = __builtin_amdgcn_mfma_f32_16x16x32_f16(wo[2], bh2, pacc, 0, 0, 0);
            pacc = __builtin_amdgcn_mfma_f32_16x16x32_f16(wo[3], bh3, pacc, 0, 0, 0);
            if (act) {
                float a0 = pacc[0], a1 = pacc[1], a2 = pacc[2], a3 = pacc[3];
                if (k == 0) {
                    float4 av; av.x = a0; av.y = a1; av.z = a2; av.w = a3;
                    *(float4*)(out + (size_t)Bq * Hq + Bq +
                               (size_t)(row0 + n16) * Fq + mt * 16 + kg * 4) = av;
                }
                err_ += fabsf(a0 * a0 - tsv.x * tsv.x);
                err_ += fabsf(a1 * a1 - tsv.y * tsv.y);
                err_ += fabsf(a2 * a2 - tsv.z * tsv.z);
                err_ += fabsf(a3 * a3 - tsv.w * tsv.w);
                if (k < Tq - 1)
                    tsv = *(const float4*)(ts + (size_t)(row0 + n16) * Tq * Fq +
                                           (size_t)(Tq - 2 - k) * Fq +
                                           mt * 16 + kg * 4);
            }
        }
        {   // pointwise
            float gi = sel4(acc[0], us);
            float gf = sel4(acc[1], us);
            float gg = sel4(acc[2], us);
            float go = sel4(acc[3], us);
            float i_ = rcpf_(1.f + exp2f_(-gi));
            float f_ = rcpf_(1.f + exp2f_(-gf));
            float g_ = 1.f - 2.f * rcpf_(exp2f_(gg) + 1.f);
            float o_ = rcpf_(1.f + exp2f_(-go));
            c_ = f_ * c_ + i_ * g_;
            float th = 1.f - 2.f * rcpf_(exp2f_(c_ * TWO_LOG2E) + 1.f);
            hT[pk ^ 1][zr][wv * 16 + un] = (f16)(o_ * th);
        }
        __syncthreads();
    }

    // rec_err reduction: waves 4..7 hold per-(row,f-slice) partials
    if (wv >= 4) {
        err_ += __shfl_xor(err_, 16, 64);   // sum over kg bit 0
        err_ += __shfl_xor(err_, 32, 64);   // sum over kg bit 1
        if (kg == 0 && act) errb[mt][n16] = err_;
    }
    __syncthreads();
    if (tid < 4) {
        float e = errb[0][tid] + errb[1][tid] + errb[2][tid] + errb[3][tid];
        out[(size_t)Bq * Hq + row0 + tid] = e;
    }
}

extern "C" void kernel_launch(void* const* d_in, const int* in_sizes, int n_in,
                              void* d_out, int out_size, void* d_ws, size_t ws_size,
                              hipStream_t stream) {
    const float* ts    = (const float*)d_in[0];
    const float* Wih_e = (const float*)d_in[1];
    const float* Whh_e = (const float*)d_in[2];
    const float* bih_e = (const float*)d_in[3];
    const float* bhh_e = (const float*)d_in[4];
    const float* Wih_d = (const float*)d_in[5];
    const float* Whh_d = (const float*)d_in[6];
    const float* bih_d = (const float*)d_in[7];
    const float* bhh_d = (const float*)d_in[8];
    const float* Wout  = (const float*)d_in[9];
    const float* bout  = (const float*)d_in[10];
    float* out = (float*)d_out;

    f16*   Wcomb = (f16*)d_ws;                                   // 128 KB
    float* bfold = (float*)((char*)d_ws + (size_t)512 * 128 * 2); // +2 KB

    hipLaunchKernelGGL(fold_kernel, dim3(128), dim3(256), 0, stream,
                       Wih_d, Whh_d, bih_d, bhh_d, Wout, bout, Wcomb, bfold);
    hipLaunchKernelGGL(lstm_ae_kernel, dim3(Bq / 4), dim3(512), 0, stream,
                       ts, Wih_e, Whh_e, bih_e, bhh_e,
                       Wout, bout, Wcomb, bfold, out);
}